// Round 6
// baseline (278.067 us; speedup 1.0000x reference)
//
#include <hip/hip_runtime.h>

typedef __bf16 bf16x8 __attribute__((ext_vector_type(8)));
typedef unsigned short u16x8 __attribute__((ext_vector_type(8)));
typedef unsigned short u16x4 __attribute__((ext_vector_type(4)));
typedef float f32x4 __attribute__((ext_vector_type(4)));

#define B_    8
#define N_    1024
#define DIM_  1024
#define H_    8
#define HD_   128
#define SCALE_ 0.08838834764831845f

__device__ __forceinline__ unsigned short f2bf(float x) {
  unsigned int u = __float_as_uint(x);
  u += 0x7fffu + ((u >> 16) & 1u);           // RNE
  return (unsigned short)(u >> 16);
}
__device__ __forceinline__ float bf2f(unsigned short h) {
  return __uint_as_float(((unsigned int)h) << 16);
}
__device__ __forceinline__ f32x4 mfma16(u16x8 a, u16x8 b, f32x4 c) {
  return __builtin_amdgcn_mfma_f32_16x16x32_bf16(
      __builtin_bit_cast(bf16x8, a), __builtin_bit_cast(bf16x8, b), c, 0, 0, 0);
}
__device__ __forceinline__ void gl_lds16(const void* g, void* l) {
  __builtin_amdgcn_global_load_lds(
      (const __attribute__((address_space(1))) unsigned int*)g,
      (__attribute__((address_space(3))) unsigned int*)l, 16, 0, 0);
}
#define SBAR() do { asm volatile("" ::: "memory"); __builtin_amdgcn_s_barrier(); \
                    asm volatile("" ::: "memory"); } while (0)
#define LGKM0() do { asm volatile("s_waitcnt lgkmcnt(0)" ::: "memory"); \
                     __builtin_amdgcn_sched_barrier(0); } while (0)
#define VMC(n)  asm volatile("s_waitcnt vmcnt(" #n ")" ::: "memory")

// ---------------- workspace layout (bytes) ----------------
#define WS_KIMG  ((size_t)0)
#define WS_VIMG  ((size_t)32 << 20)
#define WS_WIMG  ((size_t)64 << 20)
#define WS_AOIMG ((size_t)68 << 20)

// ================= prep kernels: one-time f32 -> bf16 hi/lo images =================
// K image per (bh): 16 tiles of 64 keys; each tile = 2 d-half blocks of 16KB:
// block byte = key*256 + hl*128 + ((dloc*2) ^ ((key&7)<<4))
__global__ __launch_bounds__(256)
void prep_k(const float* __restrict__ gk, char* __restrict__ kimg) {
  const int blk = blockIdx.x;                // bh*16 + it
  const int bh = blk >> 4, it = blk & 15;
  const int bb = bh >> 3, hh = bh & 7;
  const int t = threadIdx.x;
  char* base = kimg + (size_t)bh * 524288 + it * 32768;
  const float* src = gk + ((size_t)bb * N_ + it * 64) * DIM_ + hh * HD_;
  #pragma unroll
  for (int c = 0; c < 8; ++c) {
    const int idx = t + 256 * c;
    const int key = idx >> 5, dq = (idx & 31) * 4;
    f32x4 f = *(const f32x4*)(src + (size_t)key * DIM_ + dq);
    u16x4 h, g;
    #pragma unroll
    for (int j = 0; j < 4; ++j) {
      unsigned short hv = f2bf(f[j]);
      h[j] = hv;
      g[j] = f2bf(f[j] - bf2f(hv));
    }
    const int dh = dq >> 6, dloc = dq & 63;
    const int off = (dloc * 2) ^ ((key & 7) << 4);
    char* dst = base + dh * 16384 + key * 256;
    *(u16x4*)(dst + off) = h;
    *(u16x4*)(dst + 128 + off) = g;
  }
}

// V image per (bh, vtile of 32 keys): 16KB = [hi 8KB | lo 8KB],
// plane byte: (d*64 + key*2) ^ ((d&7)<<4)
__global__ __launch_bounds__(256)
void prep_v(const float* __restrict__ gv, char* __restrict__ vimg) {
  __shared__ float tile[32][132];
  const int blk = blockIdx.x;                // bh*32 + kt
  const int bh = blk >> 5, kt = blk & 31;
  const int bb = bh >> 3, hh = bh & 7;
  const int t = threadIdx.x;
  const float* src = gv + ((size_t)bb * N_ + kt * 32) * DIM_ + hh * HD_;
  #pragma unroll
  for (int c = 0; c < 4; ++c) {
    const int idx = t + 256 * c;
    const int key = idx >> 5, dq = (idx & 31) * 4;
    *(f32x4*)&tile[key][dq] = *(const f32x4*)(src + (size_t)key * DIM_ + dq);
  }
  __syncthreads();
  char* base = vimg + (size_t)bh * 524288 + kt * 16384;
  #pragma unroll
  for (int c = 0; c < 2; ++c) {
    const int oc = t + 256 * c;              // 0..511
    const int d = oc >> 2, kc = oc & 3;
    u16x8 h, g;
    #pragma unroll
    for (int j = 0; j < 8; ++j) {
      float x = tile[kc * 8 + j][d];
      unsigned short hv = f2bf(x);
      h[j] = hv;
      g[j] = f2bf(x - bf2f(hv));
    }
    const int off = (d * 64 + kc * 16) ^ ((d & 7) << 4);
    *(u16x8*)(base + off) = h;
    *(u16x8*)(base + 8192 + off) = g;
  }
}

// W image in proj-staging layout: per (nt 0..15, st 0..31): 64 rows x 128B,
// row byte = ((hl*64 + kl*2) ^ ((rl&7)<<4))
__global__ __launch_bounds__(256)
void prep_w(const float* __restrict__ gw, char* __restrict__ wimg) {
  const int idx = blockIdx.x * 256 + threadIdx.x;  // 0..131071
  const int row = idx >> 7, c0 = (idx & 127) * 8;
  const float* s = gw + (size_t)row * DIM_ + c0;
  f32x4 f0 = *(const f32x4*)s;
  f32x4 f1 = *(const f32x4*)(s + 4);
  u16x8 h, g;
  #pragma unroll
  for (int j = 0; j < 8; ++j) {
    float x = j < 4 ? f0[j] : f1[j - 4];
    unsigned short hv = f2bf(x);
    h[j] = hv;
    g[j] = f2bf(x - bf2f(hv));
  }
  const int nt = row >> 6, rl = row & 63;
  const int st = c0 >> 5, kl = c0 & 31;
  char* base = wimg + ((size_t)(nt * 32 + st) * 64 + rl) * 128;
  const int swz = (rl & 7) << 4;
  *(u16x8*)(base + ((kl * 2) ^ swz)) = h;
  *(u16x8*)(base + ((64 + kl * 2) ^ swz)) = g;
}

// ================= attention kernel (1024 threads, 16 waves) =================
struct K1Smem {
  unsigned short p[64 * 1024];            // 131072 B: p[row][key] bf16, byte ^ ((row&7)<<4)
  union {
    char kb[2][16384];                    // K half-d tiles (dbuf)
    char vt[2][16384];                    // V tiles (dbuf)
    struct { char pad[16384]; float partial[4][64]; float rinv[64]; } pp;
  } u;
};

__global__ __launch_bounds__(1024, 4)
void attn_kernel(const float* __restrict__ gq, const char* __restrict__ kimg,
                 const char* __restrict__ vimg, float* __restrict__ gattn,
                 char* __restrict__ aoimg) {
  __shared__ K1Smem sm;
  const int bid = blockIdx.x;
  const int xcd = bid & 7, slot = bid >> 3;
  const int bh = xcd + 8 * (slot >> 4);
  const int qt = slot & 15;
  const int bb = bh >> 3, hh = bh & 7;

  const int tid = threadIdx.x;
  const int wid = tid >> 6, lane = tid & 63;
  const int rg = wid >> 2;                   // 0..3: row group (16 rows)
  const int kg = wid & 3;                    // 0..3: key group (QK) / d group (PV)
  const int l15 = lane & 15, l4 = lane >> 4;

  const char* kimg_bh = kimg + (size_t)bh * 524288;
  const char* vimg_bh = vimg + (size_t)bh * 524288;

  auto issueK = [&](int s) {                 // 16KB tile s -> kb[s&1]
    const char* src = kimg_bh + s * 16384 + wid * 1024 + lane * 16;
    gl_lds16(src, sm.u.kb[s & 1] + wid * 1024);
  };
  auto issueV = [&](int kt) {                // 16KB tile kt -> vt[kt&1]
    const char* src = vimg_bh + kt * 16384 + wid * 1024 + lane * 16;
    gl_lds16(src, sm.u.vt[kt & 1] + wid * 1024);
  };

  issueK(0);                                 // flies during Q conversion

  // ---------------- Q fragments (16 rows/wave, pre-scaled, hi/lo split) ----------------
  u16x8 qhi[4], qlo[4];
  {
    const int qrow = qt * 64 + rg * 16 + l15;
    const float* qp = gq + ((size_t)bb * N_ + qrow) * DIM_ + hh * HD_;
    #pragma unroll
    for (int t = 0; t < 4; ++t) {
      const int d0 = t * 32 + l4 * 8;
      f32x4 f0 = *(const f32x4*)(qp + d0);
      f32x4 f1 = *(const f32x4*)(qp + d0 + 4);
      #pragma unroll
      for (int j = 0; j < 8; ++j) {
        float x = (j < 4 ? f0[j] : f1[j - 4]) * SCALE_;
        unsigned short hi = f2bf(x);
        qhi[t][j] = hi;
        qlo[t][j] = f2bf(x - bf2f(hi));
      }
    }
  }

  issueK(1);
  VMC(1);                                    // K0 landed (K1 in flight)
  SBAR();

  // ---------------- Phase 1: S = K Q^T (swapped: lane holds 4 keys x 1 qrow) ----------------
  float lsum = 0.f;
  const int key16 = kg * 16 + l15;
  const int kswz = (key16 & 7) << 4;
  const char* krow0 = sm.u.kb[0] + key16 * 256;
  const char* krow1 = sm.u.kb[1] + key16 * 256;
  const int prow_i = rg * 16 + l15;
  char* const prow = (char*)sm.p + prow_i * 2048;
  const int pswz = (prow_i & 7) << 4;

  f32x4 a0, a1, a2;
  #pragma unroll 2
  for (int s = 0; s < 32; ++s) {
    const int dh = s & 1;
    if (s >= 1 && s < 31) issueK(s + 1);     // kb[(s+1)&1]: its readers done last iter
    else if (s == 31) issueV(0);             // vt[0] aliases kb[0]: dead since s==30
    const char* krow = dh ? krow1 : krow0;
    u16x8 khi[2], klo[2];
    #pragma unroll
    for (int tl = 0; tl < 2; ++tl) {
      const int off = (tl * 64 + l4 * 16) ^ kswz;
      khi[tl] = *(const u16x8*)(krow + off);
      klo[tl] = *(const u16x8*)(krow + 128 + off);
    }
    if (dh == 0) {
      a0 = f32x4{0.f, 0.f, 0.f, 0.f};
      a1 = f32x4{0.f, 0.f, 0.f, 0.f};
      a2 = f32x4{0.f, 0.f, 0.f, 0.f};
    }
    __builtin_amdgcn_s_setprio(1);
    #pragma unroll
    for (int tl = 0; tl < 2; ++tl) {
      const int t = dh * 2 + tl;
      a0 = mfma16(khi[tl], qhi[t], a0);
      a1 = mfma16(klo[tl], qhi[t], a1);
      a2 = mfma16(khi[tl], qlo[t], a2);
    }
    __builtin_amdgcn_s_setprio(0);
    if (dh == 1) {
      const int keyb = ((s >> 1) * 64 + kg * 16 + l4 * 4) * 2;
      u16x4 pk;
      float ls = 0.f;
      #pragma unroll
      for (int r = 0; r < 4; ++r) {
        float sv = (a0[r] + a1[r]) + a2[r];
        sv = fminf(sv, 60.0f);
        float p = __expf(sv);
        ls += p;
        pk[r] = f2bf(p);
      }
      lsum += ls;
      *(u16x4*)(prow + (keyb ^ pswz)) = pk;
    }
    if (s < 31) VMC(0);                      // next K tile landed (hid under segment)
    SBAR();
  }

  // ---------------- rowsums -> partial -> rinv ----------------
  {
    float s0 = lsum;
    s0 += __shfl_xor(s0, 16);
    s0 += __shfl_xor(s0, 32);
    if (lane < 16) sm.u.pp.partial[kg][rg * 16 + lane] = s0;
  }
  LGKM0();
  SBAR();
  if (tid < 64) {
    float t4 = sm.u.pp.partial[0][tid] + sm.u.pp.partial[1][tid] +
               sm.u.pp.partial[2][tid] + sm.u.pp.partial[3][tid];
    sm.u.pp.rinv[tid] = 1.0f / t4;
  }
  LGKM0();
  SBAR();
  float rvf[4];
  #pragma unroll
  for (int r = 0; r < 4; ++r)
    rvf[r] = sm.u.pp.rinv[rg * 16 + l4 * 4 + r];
  const bool writer = (kg == 0);
  float rvw = 0.f;
  if (writer) rvw = sm.u.pp.rinv[prow_i];
  LGKM0();                                   // rinv reads done before vt[1] overwrite
  VMC(0);                                    // V0 landed
  SBAR();

  // ---------------- Phase 2: PV (dbuf vt) + fused attn write from pa regs ----------------
  f32x4 oacc[2];
  oacc[0] = f32x4{0.f, 0.f, 0.f, 0.f};
  oacc[1] = f32x4{0.f, 0.f, 0.f, 0.f};

  float* arow = nullptr;
  if (writer)
    arow = gattn + ((size_t)bh * N_ + qt * 64 + prow_i) * N_ + l4 * 8;

  #pragma unroll 2
  for (int kt = 0; kt < 32; ++kt) {
    if (kt < 31) issueV(kt + 1);
    const char* vbase = sm.u.vt[kt & 1];
    u16x8 vh[2], vl[2];
    #pragma unroll
    for (int ct = 0; ct < 2; ++ct) {
      const int d = kg * 32 + ct * 16 + l15;
      const int off = (d * 64 + l4 * 16) ^ ((d & 7) << 4);
      vh[ct] = *(const u16x8*)(vbase + off);
      vl[ct] = *(const u16x8*)(vbase + 8192 + off);
    }
    u16x8 pa = *(const u16x8*)(prow + ((kt * 64 + l4 * 16) ^ pswz));
    __builtin_amdgcn_s_setprio(1);
    #pragma unroll
    for (int ct = 0; ct < 2; ++ct) {
      oacc[ct] = mfma16(pa, vh[ct], oacc[ct]);
      oacc[ct] = mfma16(pa, vl[ct], oacc[ct]);
    }
    __builtin_amdgcn_s_setprio(0);
    if (writer) {
      f32x4 o0, o1;
      o0[0] = bf2f(pa[0]) * rvw; o0[1] = bf2f(pa[1]) * rvw;
      o0[2] = bf2f(pa[2]) * rvw; o0[3] = bf2f(pa[3]) * rvw;
      o1[0] = bf2f(pa[4]) * rvw; o1[1] = bf2f(pa[5]) * rvw;
      o1[2] = bf2f(pa[6]) * rvw; o1[3] = bf2f(pa[7]) * rvw;
      __builtin_nontemporal_store(o0, (f32x4*)(arow + kt * 32));
      __builtin_nontemporal_store(o1, (f32x4*)(arow + kt * 32 + 4));
    }
    LGKM0();
    if (kt < 31) {
      if (writer) { VMC(2); }                // leave the 2 attn stores in flight
      else        { VMC(0); }
    }
    SBAR();
  }

  // ---------------- epilogue: ao -> proj-image layout (bf16 hi/lo) ----------------
  {
    char* aobase = aoimg + ((size_t)((bb * 16 + qt) * 32 + hh * 4 + kg)) * 8192;
    #pragma unroll
    for (int ct = 0; ct < 2; ++ct) {
      const int colloc = ct * 16 + l15;      // k-local 0..31 within this step-tile
      #pragma unroll
      for (int r = 0; r < 4; ++r) {
        const int rl = rg * 16 + l4 * 4 + r;
        const int swz = (rl & 7) << 4;
        float val = oacc[ct][r] * rvf[r];
        unsigned short hv = f2bf(val);
        unsigned short lv = f2bf(val - bf2f(hv));
        char* rp = aobase + rl * 128;
        __builtin_nontemporal_store(hv, (unsigned short*)(rp + ((colloc * 2) ^ swz)));
        __builtin_nontemporal_store(lv, (unsigned short*)(rp + ((64 + colloc * 2) ^ swz)));
      }
    }
  }
}

// ================= K2: out = ao @ W^T + b (64x64 tiles, 2048 blocks) =================
struct K2Smem {
  char A[2][8192];
  char Bm[2][8192];
};

__global__ __launch_bounds__(512)
void proj_kernel(const char* __restrict__ aoimg, const char* __restrict__ wimg,
                 const float* __restrict__ gbias, float* __restrict__ gout) {
  __shared__ K2Smem sm;
  // 2048 blocks = 128 mt x 16 nt. Bijective XCD swizzle: each XCD owns 2 nt
  // columns (W tiles 512 KB -> L2-resident per XCD), mt sweeps within.
  const int orig = blockIdx.x;
  const int xcd = orig & 7, idx = orig >> 3;     // idx 0..255
  const int nt = xcd * 2 + (idx >> 7);           // 0..15
  const int mt = idx & 127;                      // 0..127
  const int tid = threadIdx.x;
  const int wid = tid >> 6, lane = tid & 63;
  const int wr = wid >> 2, wc = wid & 3;     // wave tile: 32 rows x 16 cols
  const int l15 = lane & 15, l4 = lane >> 4;

  auto issue = [&](int s) {
    const char* sa = aoimg + ((size_t)(mt * 32 + s)) * 8192 + wid * 1024 + lane * 16;
    gl_lds16(sa, sm.A[s & 1] + wid * 1024);
    const char* sb = wimg + ((size_t)(nt * 32 + s)) * 8192 + wid * 1024 + lane * 16;
    gl_lds16(sb, sm.Bm[s & 1] + wid * 1024);
  };

  f32x4 acc[2];
  acc[0] = f32x4{0.f, 0.f, 0.f, 0.f};
  acc[1] = f32x4{0.f, 0.f, 0.f, 0.f};

  issue(0);
  VMC(0);
  SBAR();
  #pragma unroll 2
  for (int s = 0; s < 32; ++s) {
    if (s < 31) issue(s + 1);
    const char* Ab = sm.A[s & 1];
    const char* Bb = sm.Bm[s & 1];
    u16x8 ah[2], al[2], bh, bl;
    #pragma unroll
    for (int t = 0; t < 2; ++t) {
      const int row = wr * 32 + t * 16 + l15;
      const char* rp = Ab + row * 128;
      const int swz = (row & 7) << 4;
      ah[t] = *(const u16x8*)(rp + ((l4 * 16) ^ swz));
      al[t] = *(const u16x8*)(rp + ((64 + l4 * 16) ^ swz));
    }
    {
      const int col = wc * 16 + l15;
      const char* rp = Bb + col * 128;
      const int swz = (col & 7) << 4;
      bh = *(const u16x8*)(rp + ((l4 * 16) ^ swz));
      bl = *(const u16x8*)(rp + ((64 + l4 * 16) ^ swz));
    }
    __builtin_amdgcn_s_setprio(1);
    #pragma unroll
    for (int i = 0; i < 2; ++i) {
      acc[i] = mfma16(ah[i], bh, acc[i]);
      acc[i] = mfma16(ah[i], bl, acc[i]);
      acc[i] = mfma16(al[i], bh, acc[i]);
    }
    __builtin_amdgcn_s_setprio(0);
    LGKM0();
    if (s < 31) VMC(0);
    SBAR();
  }

  const int col = nt * 64 + wc * 16 + l15;
  const float bv = gbias[col];
  #pragma unroll
  for (int i = 0; i < 2; ++i) {
    float* dst = gout + (size_t)(mt * 64 + wr * 32 + i * 16 + l4 * 4) * DIM_ + col;
    #pragma unroll
    for (int r = 0; r < 4; ++r)
      dst[(size_t)r * DIM_] = acc[i][r] + bv;
  }
}

extern "C" void kernel_launch(void* const* d_in, const int* in_sizes, int n_in,
                              void* d_out, int out_size, void* d_ws, size_t ws_size,
                              hipStream_t stream) {
  const float* q    = (const float*)d_in[0];
  const float* k    = (const float*)d_in[1];
  const float* v    = (const float*)d_in[2];
  const float* W    = (const float*)d_in[3];
  const float* bias = (const float*)d_in[4];
  float* out  = (float*)d_out;
  float* attn = out + (size_t)B_ * N_ * DIM_;      // outputs: [out | attn]

  char* ws = (char*)d_ws;                          // needs 100 MB
  char* kimg  = ws + WS_KIMG;
  char* vimg  = ws + WS_VIMG;
  char* wimg  = ws + WS_WIMG;
  char* aoimg = ws + WS_AOIMG;

  prep_k<<<64 * 16, 256, 0, stream>>>(k, kimg);
  prep_v<<<64 * 32, 256, 0, stream>>>(v, vimg);
  prep_w<<<512, 256, 0, stream>>>(W, wimg);
  attn_kernel<<<B_ * H_ * (N_ / 64), 1024, 0, stream>>>(q, kimg, vimg, attn, aoimg);
  proj_kernel<<<2048, 512, 0, stream>>>(aoimg, wimg, bias, out);
}